// Round 10
// baseline (262.687 us; speedup 1.0000x reference)
//
#include <hip/hip_runtime.h>
#include <stdint.h>

typedef unsigned short u16;
typedef unsigned int   u32;
typedef __attribute__((ext_vector_type(8))) short short8;
typedef __attribute__((ext_vector_type(4))) float f32x4;

__device__ __forceinline__ float bf2f(u16 h){
    return __uint_as_float(((u32)h) << 16);
}
__device__ __forceinline__ u16 f2bf(float f){
    u32 u = __float_as_uint(f);
    u += 0x7fffu + ((u >> 16) & 1u);   // RNE
    return (u16)(u >> 16);
}

// async global->LDS, 16B per lane. LDS dest must be wave-uniform base + lane*16.
__device__ __forceinline__ void gl_lds16(const void* g, void* l){
    __builtin_amdgcn_global_load_lds(
        (__attribute__((address_space(1))) void*)(uintptr_t)g,
        (__attribute__((address_space(3))) void*)(uintptr_t)l,
        16, 0, 0);
}

#define CAP 96

// -------- prep kernel: W transposes + X cast + biases + edge scatter -------
// z=0..3: 32x32 transpose tiles of W1..W4 ; z=4: grid-stride X cast (+biases
// on block (0,0)) ; z=5: bucketed edge scatter (cnt pre-zeroed by memset).
// Each block self-probes fp32-vs-bf16 from W1 / edge format from EI.
__global__ void prep_all(const void* w1, const void* w2, const void* w3,
                         const void* w4, const void* X,
                         const void* b1, const void* b2, const void* b3,
                         const void* b4, const void* av,
                         const int* __restrict__ EI, int* __restrict__ cnt,
                         int* __restrict__ buck, int E,
                         u16* o1, u16* o2, u16* o3, u16* o4,
                         u16* xbf, u16* d1, u16* d2, u16* d3, u16* d4,
                         u16* da, int NN){
    __shared__ int sf;
    __shared__ u16 tb[32][33];
    int lt = threadIdx.y * 32 + threadIdx.x;   // 0..255

    if (blockIdx.z == 5){   // edge scatter into buckets
        if (lt == 0) sf = 0;
        __syncthreads();
        if (EI[2*lt + 1] != 0) atomicOr(&sf, 1);   // int64: odd words zero
        __syncthreads();
        int fmt = sf;   // 1 = int32, 0 = int64
        for (int e = (blockIdx.y * 16 + blockIdx.x) * 256 + lt; e < E; e += 65536){
            int d = fmt ? EI[E + e] : EI[2*(E + e)];
            if ((unsigned)d < (unsigned)NN){
                int slot = atomicAdd(&cnt[d], 1);
                if (slot < CAP) buck[(size_t)d * CAP + slot] = fmt ? EI[e] : EI[2*e];
            }
        }
        return;
    }

    if (lt == 0) sf = 0;
    __syncthreads();
    {   // self-probe: fp32 stream read as u16 has exponent-range giveaway
        int huge = 0;
        const u16* w = (const u16*)w1;
        #pragma unroll
        for (int k = 0; k < 8; k++){
            u16 h = w[lt * 8 + k];
            if (((h >> 7) & 0xFF) >= 0x7F) huge = 1;
        }
        if (huge) atomicOr(&sf, 1);
    }
    __syncthreads();
    int f32 = sf;

    if (blockIdx.z == 4){   // X cast (+ bias conversion on block (0,0))
        #define CV(s,i) (f32 ? f2bf(((const float*)(s))[i]) : ((const u16*)(s))[i])
        if (blockIdx.x == 0 && blockIdx.y == 0){
            d1[lt]       = CV(b1, lt);
            d1[lt + 256] = CV(b1, lt + 256);
            d2[lt] = CV(b2, lt);
            d3[lt] = CV(b3, lt);
            d4[lt] = CV(b4, lt);
            if (lt == 0) da[0] = CV(av, 0);
        }
        #undef CV
        size_t nb8 = (size_t)NN * 64;
        size_t step = 256u * 256u;
        for (size_t i = (size_t)(blockIdx.y * 16 + blockIdx.x) * 256 + lt; i < nb8; i += step){
            short8 o;
            if (f32){
                const float* p = (const float*)X + i * 8;
                f32x4 a0 = *(const f32x4*)p;
                f32x4 a1 = *(const f32x4*)(p + 4);
                #pragma unroll
                for (int j = 0; j < 4; j++){
                    o[j]     = (short)f2bf(a0[j]);
                    o[4 + j] = (short)f2bf(a1[j]);
                }
            } else {
                o = *(const short8*)((const u16*)X + i * 8);
            }
            *(short8*)(xbf + i * 8) = o;
        }
        return;
    }

    const void* in; u16* out; int K, N;
    switch (blockIdx.z){
        case 0:  in = w1; out = o1; K = 512; N = 512; break;
        case 1:  in = w2; out = o2; K = 512; N = 256; break;
        case 2:  in = w3; out = o3; K = 256; N = 256; break;
        default: in = w4; out = o4; K = 256; N = 256; break;
    }
    int bx = blockIdx.x * 32;   // n
    int by = blockIdx.y * 32;   // k
    if (bx >= N || by >= K) return;
    int x = threadIdx.x, y = threadIdx.y;   // (32,8)
    #pragma unroll
    for (int i = 0; i < 32; i += 8){
        size_t idx = (size_t)(by + y + i) * N + bx + x;
        tb[y + i][x] = f32 ? f2bf(((const float*)in)[idx]) : ((const u16*)in)[idx];
    }
    __syncthreads();
    #pragma unroll
    for (int i = 0; i < 32; i += 8)
        out[(size_t)(bx + y + i) * K + by + x] = tb[x][y + i];
}

// ---------------- MFMA GEMM (m97 structure + XCD swizzle) ------------------
// C[M][N] = A[M][K] * BT[N][K]^T. 128x128 tile, BK=64, 256 thr = 4 waves (2x2),
// each wave 64x64 = 4x4 16x16 frags. global_load_lds staging.
// Optional prologue (gemm1 only): dis[i] = rsqrt(cnt[i]+1), and per-slot coef
// cdis[n*CAP+s] = rsqrt(cnt[buck[s]]+1); pad slots [deg, ceil8(deg)) get
// cdis=0 and buck=last-valid -> agg needs no clamps and no dependent dis
// gather (cuts the per-group serial chain from 3 hops to 2).
#define GTN 128
#define GBK 64

template<int MODE, int OUTF>   // MODE: 0 plain,1 +bias,2 +bias+ELU; OUTF: 0 bf16,1 fp32
__global__ __launch_bounds__(256) void gemm128(
    const u16* __restrict__ A, const u16* __restrict__ BT,
    const u16* __restrict__ bias, void* __restrict__ Cv,
    int M, int K, int N, int nN,
    const int* __restrict__ cntp, float* __restrict__ disp,
    int* __restrict__ buckp, float* __restrict__ cdisp)
{
    __shared__ __align__(16) u16 As[128 * GBK];
    __shared__ __align__(16) u16 Bs[GTN * GBK];
    if (cntp){   // aggregation-coefficient prologue (overlaps across blocks)
        int stride = gridDim.x * 256;
        int gid = blockIdx.x * 256 + (int)threadIdx.x;
        for (int i = gid; i < M; i += stride)
            disp[i] = rsqrtf((float)cntp[i] + 1.0f);
        int tot = M * CAP;
        for (int i = gid; i < tot; i += stride){
            int n = i / CAP;
            int s = i - n * CAP;
            int deg = cntp[n]; if (deg > CAP) deg = CAP;
            int ng8 = (deg + 7) & ~7;
            if (s < deg){
                cdisp[i] = rsqrtf((float)cntp[buckp[i]] + 1.0f);
            } else if (s < ng8){   // pad slot: zero coef, safe index
                cdisp[i] = 0.f;
                buckp[i] = buckp[(size_t)n * CAP + deg - 1];
            }
        }
    }
    int nwg = gridDim.x;
    int flat = blockIdx.x;
    int q8 = nwg >> 3, r8 = nwg & 7;
    int xcd = flat & 7, idx8 = flat >> 3;
    int wg = (xcd < r8 ? xcd * (q8 + 1) : r8 * (q8 + 1) + (xcd - r8) * q8) + idx8;
    int bm = (wg / nN) * 128;
    int bn = (wg % nN) * GTN;

    int tid  = threadIdx.x;
    int lane = tid & 63;
    int wm   = (tid >> 7) & 1;
    int wn   = (tid >> 6) & 1;

    f32x4 acc[4][4] = {};

    int srow = tid >> 3;
    int scol = (tid & 7) * 8;
    const u16* aP = A  + (size_t)(bm + srow) * K + scol;
    const u16* bP = BT + (size_t)(bn + srow) * K + scol;
    u16* lA = &As[tid * 8];
    u16* lB = &Bs[tid * 8];

    int q   = lane >> 4;
    int r16 = lane & 15;
    const u16* ra = &As[(wm*64 + r16) * GBK + q*8];
    const u16* rb = &Bs[(wn*64 + r16) * GBK + q*8];

    for (int k0 = 0; k0 < K; k0 += GBK){
        #pragma unroll
        for (int r = 0; r < 4; r++){
            gl_lds16(aP + (size_t)r*32*K + k0, lA + r*32*GBK);
            gl_lds16(bP + (size_t)r*32*K + k0, lB + r*32*GBK);
        }
        __syncthreads();
        #pragma unroll
        for (int kk = 0; kk < 2; kk++){
            short8 af[4], bf[4];
            #pragma unroll
            for (int i = 0; i < 4; i++) af[i] = *(const short8*)(ra + i*16*GBK + kk*32);
            #pragma unroll
            for (int j = 0; j < 4; j++) bf[j] = *(const short8*)(rb + j*16*GBK + kk*32);
            #pragma unroll
            for (int i = 0; i < 4; i++)
                #pragma unroll
                for (int j = 0; j < 4; j++)
                    acc[i][j] = __builtin_amdgcn_mfma_f32_16x16x32_bf16(af[i], bf[j], acc[i][j], 0, 0, 0);
        }
        __syncthreads();
    }

    int q4 = q * 4;
    #pragma unroll
    for (int i = 0; i < 4; i++){
        #pragma unroll
        for (int j = 0; j < 4; j++){
            int gcol = bn + wn*64 + j*16 + r16;
            float bvv = (MODE >= 1) ? bf2f(bias[gcol]) : 0.f;
            #pragma unroll
            for (int r = 0; r < 4; r++){
                int grow = bm + wm*64 + i*16 + q4 + r;
                if (grow < M){
                    float v = acc[i][j][r] + bvv;
                    if (MODE == 2) v = (v > 0.f) ? v : expm1f(v);
                    if (OUTF) ((float*)Cv)[(size_t)grow * N + gcol] = v;
                    else      ((u16*)Cv)[(size_t)grow * N + gcol] = f2bf(v);
                }
            }
        }
    }
}

// ---------------- fused projection MLP: OUT = ELU(Q@W3+b3)@W4+b4 -----------
// BM=64 row-block per workgroup; T (64x256 bf16) lives in LDS between phases.
// 4 waves 2x2; wave-tile 32x128 => acc[2][8].
__global__ __launch_bounds__(256) void gemm34(
    const u16* __restrict__ Q, const u16* __restrict__ W3T,
    const u16* __restrict__ W4T, const u16* __restrict__ b3,
    const u16* __restrict__ b4, float* __restrict__ OUT, int M)
{
    __shared__ __align__(16) u16 As[64 * 64];     //  8 KB
    __shared__ __align__(16) u16 Bs[256 * 64];    // 32 KB
    __shared__ __align__(16) u16 T[64 * 256];     // 32 KB
    int nwg = gridDim.x;
    int flat = blockIdx.x;
    int q8 = nwg >> 3, r8 = nwg & 7;
    int xcd = flat & 7, idx8 = flat >> 3;
    int wg = (xcd < r8 ? xcd * (q8 + 1) : r8 * (q8 + 1) + (xcd - r8) * q8) + idx8;
    int bm = wg * 64;

    int tid  = threadIdx.x;
    int lane = tid & 63;
    int wm   = (tid >> 7) & 1;
    int wn   = (tid >> 6) & 1;
    int q    = lane >> 4;
    int r16  = lane & 15;
    int q4   = q * 4;
    int srow = tid >> 3;
    int scol = (tid & 7) * 8;

    u16* lA = &As[tid * 8];
    u16* lB = &Bs[tid * 8];
    const u16* ra = &As[(wm*32 + r16) * 64 + q*8];
    const u16* rb = &Bs[(wn*128 + r16) * 64 + q*8];

    f32x4 acc[2][8];

    // ---- phase 1: T = ELU(Q[bm:bm+64] @ W3 + b3) ----
    #pragma unroll
    for (int i = 0; i < 2; i++)
        #pragma unroll
        for (int j = 0; j < 8; j++) acc[i][j] = (f32x4){0,0,0,0};
    {
        const u16* aP = Q   + (size_t)(bm + srow) * 256 + scol;
        const u16* bP = W3T + (size_t)srow * 256 + scol;
        for (int ks = 0; ks < 4; ks++){
            int k0 = ks * 64;
            #pragma unroll
            for (int r = 0; r < 2; r++)
                gl_lds16(aP + (size_t)r*32*256 + k0, lA + r*32*64);
            #pragma unroll
            for (int r = 0; r < 8; r++)
                gl_lds16(bP + (size_t)r*32*256 + k0, lB + r*32*64);
            __syncthreads();
            #pragma unroll
            for (int kk = 0; kk < 2; kk++){
                short8 af[2], bf[8];
                #pragma unroll
                for (int i = 0; i < 2; i++) af[i] = *(const short8*)(ra + i*16*64 + kk*32);
                #pragma unroll
                for (int j = 0; j < 8; j++) bf[j] = *(const short8*)(rb + j*16*64 + kk*32);
                #pragma unroll
                for (int i = 0; i < 2; i++)
                    #pragma unroll
                    for (int j = 0; j < 8; j++)
                        acc[i][j] = __builtin_amdgcn_mfma_f32_16x16x32_bf16(af[i], bf[j], acc[i][j], 0, 0, 0);
            }
            __syncthreads();
        }
    }
    #pragma unroll
    for (int i = 0; i < 2; i++){
        #pragma unroll
        for (int j = 0; j < 8; j++){
            int lc = wn*128 + j*16 + r16;
            float bvv = bf2f(b3[lc]);
            #pragma unroll
            for (int r = 0; r < 4; r++){
                int lr = wm*32 + i*16 + q4 + r;
                float v = acc[i][j][r] + bvv;
                v = (v > 0.f) ? v : expm1f(v);
                T[lr * 256 + lc] = f2bf(v);
            }
        }
    }
    __syncthreads();

    // ---- phase 2: OUT = T @ W4 + b4 ----
    #pragma unroll
    for (int i = 0; i < 2; i++)
        #pragma unroll
        for (int j = 0; j < 8; j++) acc[i][j] = (f32x4){0,0,0,0};
    {
        const u16* bP = W4T + (size_t)srow * 256 + scol;
        for (int ks = 0; ks < 4; ks++){
            int k0 = ks * 64;
            #pragma unroll
            for (int r = 0; r < 8; r++)
                gl_lds16(bP + (size_t)r*32*256 + k0, lB + r*32*64);
            __syncthreads();
            #pragma unroll
            for (int kk = 0; kk < 2; kk++){
                short8 af[2], bf[8];
                #pragma unroll
                for (int i = 0; i < 2; i++)
                    af[i] = *(const short8*)&T[(wm*32 + i*16 + r16) * 256 + k0 + kk*32 + q*8];
                #pragma unroll
                for (int j = 0; j < 8; j++) bf[j] = *(const short8*)(rb + j*16*64 + kk*32);
                #pragma unroll
                for (int i = 0; i < 2; i++)
                    #pragma unroll
                    for (int j = 0; j < 8; j++)
                        acc[i][j] = __builtin_amdgcn_mfma_f32_16x16x32_bf16(af[i], bf[j], acc[i][j], 0, 0, 0);
            }
            __syncthreads();
        }
    }
    #pragma unroll
    for (int i = 0; i < 2; i++){
        #pragma unroll
        for (int j = 0; j < 8; j++){
            int lc = wn*128 + j*16 + r16;
            float bvv = bf2f(b4[lc]);
            #pragma unroll
            for (int r = 0; r < 4; r++){
                int grow = bm + wm*32 + i*16 + q4 + r;
                if (grow < M)
                    OUT[(size_t)grow * 256 + lc] = acc[i][j][r] + bvv;
            }
        }
    }
}

// -------- pull aggregation: bucketed, feature-chunked + XCD-pinned ---------
// chunk = bid % NCH; with round-robin block->XCD mapping each XCD gathers only
// its 2.56 MB feature slice (L2-resident).
// Slots padded to groups of 8 IN MEMORY (cdis=0, safe idx) by gemm1 prologue:
// per-group loads are two parallel coalesced streams (bk, cd) -> row gather.
// No clamps, no dependent dis gather. 2-hop chain per group.
// NOTE: plain launch_bounds(256) — (256,8) forced 32-VGPR spill-to-scratch
// (R8: 1.5 GB scratch traffic, 345 us).
template<int F, int CH>
__global__ __launch_bounds__(256) void agg_b(
    const u16* __restrict__ XW, const float* __restrict__ dis,
    const int* __restrict__ cnt, const int* __restrict__ buck,
    const float* __restrict__ cdis, const u16* __restrict__ bias,
    const u16* __restrict__ aptr, u16* __restrict__ out, int N)
{
    constexpr int NCH = F / CH;          // 8 (F=512) or 4 (F=256)
    constexpr int LPN = CH / 8;          // 8 lanes per node
    constexpr int NPB = 256 / LPN;       // 32 nodes per block
    int bid = blockIdx.x;
    int chunk = bid % NCH;
    int node = (bid / NCH) * NPB + ((int)threadIdx.x / LPN);
    if (node >= N) return;
    int tf = chunk * CH + ((int)threadIdx.x % LPN) * 8;
    float a  = bf2f(aptr[0]);
    float di = dis[node];
    int dgc = cnt[node];
    int deg = dgc < CAP ? dgc : CAP;
    const int*   bk = buck + (size_t)node * CAP;
    const float* cd = cdis + (size_t)node * CAP;
    float acc[8] = {0,0,0,0,0,0,0,0};
    int ng = (deg + 7) >> 3;
    int si[8]; float ci[8];
    if (ng > 0){   // slots are memory-padded: straight coalesced loads
        #pragma unroll
        for (int u = 0; u < 8; u++) si[u] = bk[u];
        #pragma unroll
        for (int u = 0; u < 8; u++) ci[u] = cd[u];
    }
    for (int g = 0; g < ng; g++){
        short8 vi[8];
        #pragma unroll
        for (int u = 0; u < 8; u++)
            vi[u] = *(const short8*)(XW + (size_t)si[u] * F + tf);
        int sn[8]; float cn[8];
        bool more = (g + 1) < ng;
        if (more){   // prefetch next group (parallel streams, no dependency)
            int base = (g + 1) * 8;
            #pragma unroll
            for (int u = 0; u < 8; u++) sn[u] = bk[base + u];
            #pragma unroll
            for (int u = 0; u < 8; u++) cn[u] = cd[base + u];
        }
        #pragma unroll
        for (int u = 0; u < 8; u++)
            #pragma unroll
            for (int j = 0; j < 8; j++)
                acc[j] += ci[u] * bf2f((u16)vi[u][j]);
        if (more){
            #pragma unroll
            for (int u = 0; u < 8; u++){ si[u] = sn[u]; ci[u] = cn[u]; }
        }
    }
    {   // self-loop
        short8 v = *(const short8*)(XW + (size_t)node * F + tf);
        #pragma unroll
        for (int j = 0; j < 8; j++) acc[j] += di * bf2f((u16)v[j]);
    }
    short8 bv = *(const short8*)(bias + tf);
    short8 o;
    #pragma unroll
    for (int j = 0; j < 8; j++){
        float x = di * acc[j] + bf2f((u16)bv[j]);
        x = (x > 0.f) ? x : a * x;
        o[j] = (short)f2bf(x);
    }
    *(short8*)(out + (size_t)node * F + tf) = o;
}

// ---------------- launch ----------------------------------------------------
extern "C" void kernel_launch(void* const* d_in, const int* in_sizes, int n_in,
                              void* d_out, int out_size, void* d_ws, size_t ws_size,
                              hipStream_t stream)
{
    int iX=0, iEI=1, iW1=2, ib1=3, iW2=4, ib2=5, ia=6, iW3=7, ib3=8, iW4=9, ib4=10;
    {
        int jX=-1,jEI=-1,jW1=-1,jb1=-1,jW2=-1,ja=-1,jW3=-1,jW4=-1,jb2=-1,jb3=-1,jb4=-1;
        int n64k=0, n256=0;
        for (int i = 0; i < n_in; i++){
            switch (in_sizes[i]){
                case 10240000: jX = i; break;
                case 640000:   jEI = i; break;
                case 262144:   jW1 = i; break;
                case 131072:   jW2 = i; break;
                case 512:      jb1 = i; break;
                case 1:        ja = i; break;
                case 65536:    if (n64k++ == 0) jW3 = i; else jW4 = i; break;
                case 256: {
                    int k = n256++;
                    if (k == 0) jb2 = i; else if (k == 1) jb3 = i; else jb4 = i;
                } break;
                default: break;
            }
        }
        if (jX>=0&&jEI>=0&&jW1>=0&&jb1>=0&&jW2>=0&&ja>=0&&jW3>=0&&jW4>=0&&jb2>=0&&jb3>=0&&jb4>=0){
            iX=jX; iEI=jEI; iW1=jW1; ib1=jb1; iW2=jW2; ib2=jb2; ia=ja; iW3=jW3; ib3=jb3; iW4=jW4; ib4=jb4;
        }
    }
    int N = in_sizes[iX] / 512;
    int E = in_sizes[iEI] / 2;
    const int* EI = (const int*)d_in[iEI];
    float* OUT = (float*)d_out;                 // fp32 output (N*256*4 bytes)
    u16*   S   = (u16*)d_out;                   // same bytes as bf16 N x 512 scratch

    char* ws = (char*)d_ws;
    size_t off = 0;
    auto alloc = [&](size_t bytes)->char*{
        char* p = ws + off;
        off = (off + bytes + 255) & ~(size_t)255;
        return p;
    };
    int MP = N + 128;                           // row-padded for OOB tile staging
    int*   cnt  = (int*)  alloc((size_t)N*4);
    float* dis  = (float*)alloc((size_t)N*4);
    int*   buck = (int*)  alloc((size_t)N*CAP*4);   // 7.7 MB
    float* cdis = (float*)alloc((size_t)N*CAP*4);   // 7.7 MB
    u16*   WT1  = (u16*)  alloc((size_t)512*512*2);
    u16*   WT2  = (u16*)  alloc((size_t)256*512*2);
    u16*   WT3  = (u16*)  alloc((size_t)256*256*2);
    u16*   WT4  = (u16*)  alloc((size_t)256*256*2);
    u16*   b1c  = (u16*)  alloc((size_t)512*2);
    u16*   b2c  = (u16*)  alloc((size_t)256*2);
    u16*   b3c  = (u16*)  alloc((size_t)256*2);
    u16*   b4c  = (u16*)  alloc((size_t)256*2);
    u16*   ac   = (u16*)  alloc((size_t)8*2);
    u16*   Xbf  = (u16*)  alloc((size_t)MP*512*2);  // 20.6 MB
    u16*   h1   = (u16*)  alloc((size_t)MP*512*2);  // 20.6 MB
    u16*   P    = (u16*)  alloc((size_t)MP*256*2);  // 10.3 MB
    u16*   Q    = (u16*)  alloc((size_t)MP*256*2);  // 10.3 MB
    if (ws_size < off) return;

    hipMemsetAsync(cnt, 0, (size_t)N*4, stream);

    // prep: W^T + X cast + biases + edge scatter in one launch
    prep_all<<<dim3(16, 16, 6), dim3(32, 8), 0, stream>>>(
        d_in[iW1], d_in[iW2], d_in[iW3], d_in[iW4], d_in[iX],
        d_in[ib1], d_in[ib2], d_in[ib3], d_in[ib4], d_in[ia],
        EI, cnt, buck, E,
        WT1, WT2, WT3, WT4, Xbf, b1c, b2c, b3c, b4c, ac, N);

    int gm128 = (N + 127) / 128;          // 157
    int gm64  = (N + 63) / 64;            // 313
    int nodeb = (N + 31) / 32;            // 625

    // layer 1: Xbf @ W1 -> S (+ dis/cdis/pad prologue), aggregate -> h1
    gemm128<0,0><<<gm128*4, 256, 0, stream>>>(Xbf, WT1, nullptr, S, N, 512, 512, 4,
                                              cnt, dis, buck, cdis);
    agg_b<512,64><<<nodeb*8, 256, 0, stream>>>(S, dis, cnt, buck, cdis, b1c, ac, h1, N);

    // layer 2: h1 @ W2 -> P ; aggregate -> Q
    gemm128<0,0><<<gm128*2, 256, 0, stream>>>(h1, WT2, nullptr, P, N, 512, 256, 2,
                                              nullptr, nullptr, nullptr, nullptr);
    agg_b<256,64><<<nodeb*4, 256, 0, stream>>>(P, dis, cnt, buck, cdis, b2c, ac, Q, N);

    // projection MLP fused: OUT = ELU(Q@W3+b3)@W4 + b4
    gemm34<<<gm64, 256, 0, stream>>>(Q, WT3, WT4, b3c, b4c, OUT, N);
}

// Round 11
// 240.890 us; speedup vs baseline: 1.0905x; 1.0905x over previous
//
#include <hip/hip_runtime.h>
#include <stdint.h>

typedef unsigned short u16;
typedef unsigned int   u32;
typedef __attribute__((ext_vector_type(8))) short short8;
typedef __attribute__((ext_vector_type(4))) float f32x4;

__device__ __forceinline__ float bf2f(u16 h){
    return __uint_as_float(((u32)h) << 16);
}
__device__ __forceinline__ u16 f2bf(float f){
    u32 u = __float_as_uint(f);
    u += 0x7fffu + ((u >> 16) & 1u);   // RNE
    return (u16)(u >> 16);
}

// async global->LDS, 16B per lane. LDS dest must be wave-uniform base + lane*16.
__device__ __forceinline__ void gl_lds16(const void* g, void* l){
    __builtin_amdgcn_global_load_lds(
        (__attribute__((address_space(1))) void*)(uintptr_t)g,
        (__attribute__((address_space(3))) void*)(uintptr_t)l,
        16, 0, 0);
}

#define CAP 96

// -------- prep kernel: W transposes + X cast + biases + edge scatter -------
// z=0..3: 32x32 transpose tiles of W1..W4 ; z=4: grid-stride X cast (+biases
// on block (0,0)) ; z=5: bucketed edge scatter (cnt pre-zeroed by memset).
// Each block self-probes fp32-vs-bf16 from W1 / edge format from EI.
__global__ void prep_all(const void* w1, const void* w2, const void* w3,
                         const void* w4, const void* X,
                         const void* b1, const void* b2, const void* b3,
                         const void* b4, const void* av,
                         const int* __restrict__ EI, int* __restrict__ cnt,
                         int* __restrict__ buck, int E,
                         u16* o1, u16* o2, u16* o3, u16* o4,
                         u16* xbf, u16* d1, u16* d2, u16* d3, u16* d4,
                         u16* da, int NN){
    __shared__ int sf;
    __shared__ u16 tb[32][33];
    int lt = threadIdx.y * 32 + threadIdx.x;   // 0..255

    if (blockIdx.z == 5){   // edge scatter into buckets
        if (lt == 0) sf = 0;
        __syncthreads();
        if (EI[2*lt + 1] != 0) atomicOr(&sf, 1);   // int64: odd words zero
        __syncthreads();
        int fmt = sf;   // 1 = int32, 0 = int64
        for (int e = (blockIdx.y * 16 + blockIdx.x) * 256 + lt; e < E; e += 65536){
            int d = fmt ? EI[E + e] : EI[2*(E + e)];
            if ((unsigned)d < (unsigned)NN){
                int slot = atomicAdd(&cnt[d], 1);
                if (slot < CAP) buck[(size_t)d * CAP + slot] = fmt ? EI[e] : EI[2*e];
            }
        }
        return;
    }

    if (lt == 0) sf = 0;
    __syncthreads();
    {   // self-probe: fp32 stream read as u16 has exponent-range giveaway
        int huge = 0;
        const u16* w = (const u16*)w1;
        #pragma unroll
        for (int k = 0; k < 8; k++){
            u16 h = w[lt * 8 + k];
            if (((h >> 7) & 0xFF) >= 0x7F) huge = 1;
        }
        if (huge) atomicOr(&sf, 1);
    }
    __syncthreads();
    int f32 = sf;

    if (blockIdx.z == 4){   // X cast (+ bias conversion on block (0,0))
        #define CV(s,i) (f32 ? f2bf(((const float*)(s))[i]) : ((const u16*)(s))[i])
        if (blockIdx.x == 0 && blockIdx.y == 0){
            d1[lt]       = CV(b1, lt);
            d1[lt + 256] = CV(b1, lt + 256);
            d2[lt] = CV(b2, lt);
            d3[lt] = CV(b3, lt);
            d4[lt] = CV(b4, lt);
            if (lt == 0) da[0] = CV(av, 0);
        }
        #undef CV
        size_t nb8 = (size_t)NN * 64;
        size_t step = 256u * 256u;
        for (size_t i = (size_t)(blockIdx.y * 16 + blockIdx.x) * 256 + lt; i < nb8; i += step){
            short8 o;
            if (f32){
                const float* p = (const float*)X + i * 8;
                f32x4 a0 = *(const f32x4*)p;
                f32x4 a1 = *(const f32x4*)(p + 4);
                #pragma unroll
                for (int j = 0; j < 4; j++){
                    o[j]     = (short)f2bf(a0[j]);
                    o[4 + j] = (short)f2bf(a1[j]);
                }
            } else {
                o = *(const short8*)((const u16*)X + i * 8);
            }
            *(short8*)(xbf + i * 8) = o;
        }
        return;
    }

    const void* in; u16* out; int K, N;
    switch (blockIdx.z){
        case 0:  in = w1; out = o1; K = 512; N = 512; break;
        case 1:  in = w2; out = o2; K = 512; N = 256; break;
        case 2:  in = w3; out = o3; K = 256; N = 256; break;
        default: in = w4; out = o4; K = 256; N = 256; break;
    }
    int bx = blockIdx.x * 32;   // n
    int by = blockIdx.y * 32;   // k
    if (bx >= N || by >= K) return;
    int x = threadIdx.x, y = threadIdx.y;   // (32,8)
    #pragma unroll
    for (int i = 0; i < 32; i += 8){
        size_t idx = (size_t)(by + y + i) * N + bx + x;
        tb[y + i][x] = f32 ? f2bf(((const float*)in)[idx]) : ((const u16*)in)[idx];
    }
    __syncthreads();
    #pragma unroll
    for (int i = 0; i < 32; i += 8)
        out[(size_t)(bx + y + i) * K + by + x] = tb[x][y + i];
}

// ---- coef kernel: dis + per-slot cdis + pad-fix (one slot per thread) -----
// cdis[n*CAP+s] = rsqrt(cnt[buck[s]]+1) for s<deg; pad slots [deg, ceil8(deg))
// get cdis=0 and a safe (last-valid) index so agg needs no clamps and no
// dependent dis gather. Fully parallel: 1.92M threads, ~2 gathers max each.
// (R10 lesson: this work inside gemm1's prologue cost +20us — serialized
// ahead of MFMA at low occupancy. Standalone it's latency-hidden by TLP.)
__global__ void coef(const int* __restrict__ cnt, int* __restrict__ buck,
                     float* __restrict__ dis, float* __restrict__ cdis, int N){
    int i = blockIdx.x * 256 + threadIdx.x;
    if (i < N) dis[i] = rsqrtf((float)cnt[i] + 1.0f);
    int tot = N * CAP;
    if (i < tot){
        int n = i / CAP;            // magic-mul (CAP constant)
        int s = i - n * CAP;
        int deg = cnt[n]; if (deg > CAP) deg = CAP;
        int ng8 = (deg + 7) & ~7;
        if (s < deg){
            cdis[i] = rsqrtf((float)cnt[buck[i]] + 1.0f);
        } else if (s < ng8){        // pad slot: zero coef, safe index
            cdis[i] = 0.f;
            buck[i] = buck[(size_t)n * CAP + deg - 1];
        }
    }
}

// ---------------- MFMA GEMM (m97 structure + XCD swizzle) ------------------
// C[M][N] = A[M][K] * BT[N][K]^T. 128x128 tile, BK=64, 256 thr = 4 waves (2x2),
// each wave 64x64 = 4x4 16x16 frags. global_load_lds staging.
// LDS XOR swizzle (G4): rows are 128B so ds_read_b128 used only banks 0-15
// (R10: 3.86M SQ_LDS_BANK_CONFLICT). LDS dest stays linear (gl_lds rule #21);
// the GLOBAL source col is pre-swizzled by ((srow&7)*8) elems, and reads
// apply the same byte-XOR ((r16&7)<<4). Bank-balanced -> 8-cy floor.
#define GTN 128
#define GBK 64

template<int MODE, int OUTF>   // MODE: 0 plain,1 +bias,2 +bias+ELU; OUTF: 0 bf16,1 fp32
__global__ __launch_bounds__(256) void gemm128(
    const u16* __restrict__ A, const u16* __restrict__ BT,
    const u16* __restrict__ bias, void* __restrict__ Cv,
    int M, int K, int N, int nN)
{
    __shared__ __align__(16) u16 As[128 * GBK];
    __shared__ __align__(16) u16 Bs[GTN * GBK];
    int nwg = gridDim.x;
    int flat = blockIdx.x;
    int q8 = nwg >> 3, r8 = nwg & 7;
    int xcd = flat & 7, idx8 = flat >> 3;
    int wg = (xcd < r8 ? xcd * (q8 + 1) : r8 * (q8 + 1) + (xcd - r8) * q8) + idx8;
    int bm = (wg / nN) * 128;
    int bn = (wg % nN) * GTN;

    int tid  = threadIdx.x;
    int lane = tid & 63;
    int wm   = (tid >> 7) & 1;
    int wn   = (tid >> 6) & 1;

    f32x4 acc[4][4] = {};

    int srow = tid >> 3;                              // 0..31 per staging round
    int scS  = (((tid & 7) ^ (srow & 7)) * 8);        // swizzled source col (elems)
    const u16* aP = A  + (size_t)(bm + srow) * K + scS;
    const u16* bP = BT + (size_t)(bn + srow) * K + scS;
    u16* lA = &As[tid * 8];
    u16* lB = &Bs[tid * 8];

    int q   = lane >> 4;
    int r16 = lane & 15;
    int swz = (r16 & 7) << 4;                         // byte XOR within 128-B row
    const char* raB = (const char*)&As[(wm*64 + r16) * GBK];
    const char* rbB = (const char*)&Bs[(wn*64 + r16) * GBK];

    for (int k0 = 0; k0 < K; k0 += GBK){
        #pragma unroll
        for (int r = 0; r < 4; r++){
            gl_lds16(aP + (size_t)r*32*K + k0, lA + r*32*GBK);
            gl_lds16(bP + (size_t)r*32*K + k0, lB + r*32*GBK);
        }
        __syncthreads();
        #pragma unroll
        for (int kk = 0; kk < 2; kk++){
            int co0 = (q*16 + kk*64) ^ swz;           // swizzled read col (bytes)
            short8 af[4], bf[4];
            #pragma unroll
            for (int i = 0; i < 4; i++) af[i] = *(const short8*)(raB + i*2048 + co0);
            #pragma unroll
            for (int j = 0; j < 4; j++) bf[j] = *(const short8*)(rbB + j*2048 + co0);
            #pragma unroll
            for (int i = 0; i < 4; i++)
                #pragma unroll
                for (int j = 0; j < 4; j++)
                    acc[i][j] = __builtin_amdgcn_mfma_f32_16x16x32_bf16(af[i], bf[j], acc[i][j], 0, 0, 0);
        }
        __syncthreads();
    }

    int q4 = q * 4;
    #pragma unroll
    for (int i = 0; i < 4; i++){
        #pragma unroll
        for (int j = 0; j < 4; j++){
            int gcol = bn + wn*64 + j*16 + r16;
            float bvv = (MODE >= 1) ? bf2f(bias[gcol]) : 0.f;
            #pragma unroll
            for (int r = 0; r < 4; r++){
                int grow = bm + wm*64 + i*16 + q4 + r;
                if (grow < M){
                    float v = acc[i][j][r] + bvv;
                    if (MODE == 2) v = (v > 0.f) ? v : expm1f(v);
                    if (OUTF) ((float*)Cv)[(size_t)grow * N + gcol] = v;
                    else      ((u16*)Cv)[(size_t)grow * N + gcol] = f2bf(v);
                }
            }
        }
    }
}

// ---------------- fused projection MLP: OUT = ELU(Q@W3+b3)@W4+b4 -----------
// BM=64 row-block per workgroup; T (64x256 bf16) lives in LDS between phases.
// 4 waves 2x2; wave-tile 32x128 => acc[2][8].
__global__ __launch_bounds__(256) void gemm34(
    const u16* __restrict__ Q, const u16* __restrict__ W3T,
    const u16* __restrict__ W4T, const u16* __restrict__ b3,
    const u16* __restrict__ b4, float* __restrict__ OUT, int M)
{
    __shared__ __align__(16) u16 As[64 * 64];     //  8 KB
    __shared__ __align__(16) u16 Bs[256 * 64];    // 32 KB
    __shared__ __align__(16) u16 T[64 * 256];     // 32 KB
    int nwg = gridDim.x;
    int flat = blockIdx.x;
    int q8 = nwg >> 3, r8 = nwg & 7;
    int xcd = flat & 7, idx8 = flat >> 3;
    int wg = (xcd < r8 ? xcd * (q8 + 1) : r8 * (q8 + 1) + (xcd - r8) * q8) + idx8;
    int bm = wg * 64;

    int tid  = threadIdx.x;
    int lane = tid & 63;
    int wm   = (tid >> 7) & 1;
    int wn   = (tid >> 6) & 1;
    int q    = lane >> 4;
    int r16  = lane & 15;
    int q4   = q * 4;
    int srow = tid >> 3;
    int scol = (tid & 7) * 8;

    u16* lA = &As[tid * 8];
    u16* lB = &Bs[tid * 8];
    const u16* ra = &As[(wm*32 + r16) * 64 + q*8];
    const u16* rb = &Bs[(wn*128 + r16) * 64 + q*8];

    f32x4 acc[2][8];

    // ---- phase 1: T = ELU(Q[bm:bm+64] @ W3 + b3) ----
    #pragma unroll
    for (int i = 0; i < 2; i++)
        #pragma unroll
        for (int j = 0; j < 8; j++) acc[i][j] = (f32x4){0,0,0,0};
    {
        const u16* aP = Q   + (size_t)(bm + srow) * 256 + scol;
        const u16* bP = W3T + (size_t)srow * 256 + scol;
        for (int ks = 0; ks < 4; ks++){
            int k0 = ks * 64;
            #pragma unroll
            for (int r = 0; r < 2; r++)
                gl_lds16(aP + (size_t)r*32*256 + k0, lA + r*32*64);
            #pragma unroll
            for (int r = 0; r < 8; r++)
                gl_lds16(bP + (size_t)r*32*256 + k0, lB + r*32*64);
            __syncthreads();
            #pragma unroll
            for (int kk = 0; kk < 2; kk++){
                short8 af[2], bf[8];
                #pragma unroll
                for (int i = 0; i < 2; i++) af[i] = *(const short8*)(ra + i*16*64 + kk*32);
                #pragma unroll
                for (int j = 0; j < 8; j++) bf[j] = *(const short8*)(rb + j*16*64 + kk*32);
                #pragma unroll
                for (int i = 0; i < 2; i++)
                    #pragma unroll
                    for (int j = 0; j < 8; j++)
                        acc[i][j] = __builtin_amdgcn_mfma_f32_16x16x32_bf16(af[i], bf[j], acc[i][j], 0, 0, 0);
            }
            __syncthreads();
        }
    }
    #pragma unroll
    for (int i = 0; i < 2; i++){
        #pragma unroll
        for (int j = 0; j < 8; j++){
            int lc = wn*128 + j*16 + r16;
            float bvv = bf2f(b3[lc]);
            #pragma unroll
            for (int r = 0; r < 4; r++){
                int lr = wm*32 + i*16 + q4 + r;
                float v = acc[i][j][r] + bvv;
                v = (v > 0.f) ? v : expm1f(v);
                T[lr * 256 + lc] = f2bf(v);
            }
        }
    }
    __syncthreads();

    // ---- phase 2: OUT = T @ W4 + b4 ----
    #pragma unroll
    for (int i = 0; i < 2; i++)
        #pragma unroll
        for (int j = 0; j < 8; j++) acc[i][j] = (f32x4){0,0,0,0};
    {
        const u16* bP = W4T + (size_t)srow * 256 + scol;
        for (int ks = 0; ks < 4; ks++){
            int k0 = ks * 64;
            #pragma unroll
            for (int r = 0; r < 8; r++)
                gl_lds16(bP + (size_t)r*32*256 + k0, lB + r*32*64);
            __syncthreads();
            #pragma unroll
            for (int kk = 0; kk < 2; kk++){
                short8 af[2], bf[8];
                #pragma unroll
                for (int i = 0; i < 2; i++)
                    af[i] = *(const short8*)&T[(wm*32 + i*16 + r16) * 256 + k0 + kk*32 + q*8];
                #pragma unroll
                for (int j = 0; j < 8; j++) bf[j] = *(const short8*)(rb + j*16*64 + kk*32);
                #pragma unroll
                for (int i = 0; i < 2; i++)
                    #pragma unroll
                    for (int j = 0; j < 8; j++)
                        acc[i][j] = __builtin_amdgcn_mfma_f32_16x16x32_bf16(af[i], bf[j], acc[i][j], 0, 0, 0);
            }
            __syncthreads();
        }
    }
    #pragma unroll
    for (int i = 0; i < 2; i++){
        #pragma unroll
        for (int j = 0; j < 8; j++){
            int lc = wn*128 + j*16 + r16;
            float bvv = bf2f(b4[lc]);
            #pragma unroll
            for (int r = 0; r < 4; r++){
                int grow = bm + wm*32 + i*16 + q4 + r;
                if (grow < M)
                    OUT[(size_t)grow * 256 + lc] = acc[i][j][r] + bvv;
            }
        }
    }
}

// -------- pull aggregation: bucketed, feature-chunked + XCD-pinned ---------
// chunk = bid % NCH; with round-robin block->XCD mapping each XCD gathers only
// its 2.56 MB feature slice (L2-resident).
// Slots padded to groups of 8 IN MEMORY (cdis=0, safe idx) by coef kernel:
// per-group loads are two parallel coalesced streams (bk, cd) -> row gather.
// NOTE: plain launch_bounds(256) — (256,8) forced 32-VGPR spill-to-scratch
// (R8: 1.5 GB scratch traffic, 345 us).
template<int F, int CH>
__global__ __launch_bounds__(256) void agg_b(
    const u16* __restrict__ XW, const float* __restrict__ dis,
    const int* __restrict__ cnt, const int* __restrict__ buck,
    const float* __restrict__ cdis, const u16* __restrict__ bias,
    const u16* __restrict__ aptr, u16* __restrict__ out, int N)
{
    constexpr int NCH = F / CH;          // 8 (F=512) or 4 (F=256)
    constexpr int LPN = CH / 8;          // 8 lanes per node
    constexpr int NPB = 256 / LPN;       // 32 nodes per block
    int bid = blockIdx.x;
    int chunk = bid % NCH;
    int node = (bid / NCH) * NPB + ((int)threadIdx.x / LPN);
    if (node >= N) return;
    int tf = chunk * CH + ((int)threadIdx.x % LPN) * 8;
    float a  = bf2f(aptr[0]);
    float di = dis[node];
    int dgc = cnt[node];
    int deg = dgc < CAP ? dgc : CAP;
    const int*   bk = buck + (size_t)node * CAP;
    const float* cd = cdis + (size_t)node * CAP;
    float acc[8] = {0,0,0,0,0,0,0,0};
    int ng = (deg + 7) >> 3;
    int si[8]; float ci[8];
    if (ng > 0){   // slots are memory-padded: straight coalesced loads
        #pragma unroll
        for (int u = 0; u < 8; u++) si[u] = bk[u];
        #pragma unroll
        for (int u = 0; u < 8; u++) ci[u] = cd[u];
    }
    for (int g = 0; g < ng; g++){
        short8 vi[8];
        #pragma unroll
        for (int u = 0; u < 8; u++)
            vi[u] = *(const short8*)(XW + (size_t)si[u] * F + tf);
        int sn[8]; float cn[8];
        bool more = (g + 1) < ng;
        if (more){   // prefetch next group (parallel streams, no dependency)
            int base = (g + 1) * 8;
            #pragma unroll
            for (int u = 0; u < 8; u++) sn[u] = bk[base + u];
            #pragma unroll
            for (int u = 0; u < 8; u++) cn[u] = cd[base + u];
        }
        #pragma unroll
        for (int u = 0; u < 8; u++)
            #pragma unroll
            for (int j = 0; j < 8; j++)
                acc[j] += ci[u] * bf2f((u16)vi[u][j]);
        if (more){
            #pragma unroll
            for (int u = 0; u < 8; u++){ si[u] = sn[u]; ci[u] = cn[u]; }
        }
    }
    {   // self-loop
        short8 v = *(const short8*)(XW + (size_t)node * F + tf);
        #pragma unroll
        for (int j = 0; j < 8; j++) acc[j] += di * bf2f((u16)v[j]);
    }
    short8 bv = *(const short8*)(bias + tf);
    short8 o;
    #pragma unroll
    for (int j = 0; j < 8; j++){
        float x = di * acc[j] + bf2f((u16)bv[j]);
        x = (x > 0.f) ? x : a * x;
        o[j] = (short)f2bf(x);
    }
    *(short8*)(out + (size_t)node * F + tf) = o;
}

// ---------------- launch ----------------------------------------------------
extern "C" void kernel_launch(void* const* d_in, const int* in_sizes, int n_in,
                              void* d_out, int out_size, void* d_ws, size_t ws_size,
                              hipStream_t stream)
{
    int iX=0, iEI=1, iW1=2, ib1=3, iW2=4, ib2=5, ia=6, iW3=7, ib3=8, iW4=9, ib4=10;
    {
        int jX=-1,jEI=-1,jW1=-1,jb1=-1,jW2=-1,ja=-1,jW3=-1,jW4=-1,jb2=-1,jb3=-1,jb4=-1;
        int n64k=0, n256=0;
        for (int i = 0; i < n_in; i++){
            switch (in_sizes[i]){
                case 10240000: jX = i; break;
                case 640000:   jEI = i; break;
                case 262144:   jW1 = i; break;
                case 131072:   jW2 = i; break;
                case 512:      jb1 = i; break;
                case 1:        ja = i; break;
                case 65536:    if (n64k++ == 0) jW3 = i; else jW4 = i; break;
                case 256: {
                    int k = n256++;
                    if (k == 0) jb2 = i; else if (k == 1) jb3 = i; else jb4 = i;
                } break;
                default: break;
            }
        }
        if (jX>=0&&jEI>=0&&jW1>=0&&jb1>=0&&jW2>=0&&ja>=0&&jW3>=0&&jW4>=0&&jb2>=0&&jb3>=0&&jb4>=0){
            iX=jX; iEI=jEI; iW1=jW1; ib1=jb1; iW2=jW2; ib2=jb2; ia=ja; iW3=jW3; ib3=jb3; iW4=jW4; ib4=jb4;
        }
    }
    int N = in_sizes[iX] / 512;
    int E = in_sizes[iEI] / 2;
    const int* EI = (const int*)d_in[iEI];
    float* OUT = (float*)d_out;                 // fp32 output (N*256*4 bytes)
    u16*   S   = (u16*)d_out;                   // same bytes as bf16 N x 512 scratch

    char* ws = (char*)d_ws;
    size_t off = 0;
    auto alloc = [&](size_t bytes)->char*{
        char* p = ws + off;
        off = (off + bytes + 255) & ~(size_t)255;
        return p;
    };
    int MP = N + 128;                           // row-padded for OOB tile staging
    int*   cnt  = (int*)  alloc((size_t)N*4);
    float* dis  = (float*)alloc((size_t)N*4);
    int*   buck = (int*)  alloc((size_t)N*CAP*4);   // 7.7 MB
    float* cdis = (float*)alloc((size_t)N*CAP*4);   // 7.7 MB
    u16*   WT1  = (u16*)  alloc((size_t)512*512*2);
    u16*   WT2  = (u16*)  alloc((size_t)256*512*2);
    u16*   WT3  = (u16*)  alloc((size_t)256*256*2);
    u16*   WT4  = (u16*)  alloc((size_t)256*256*2);
    u16*   b1c  = (u16*)  alloc((size_t)512*2);
    u16*   b2c  = (u16*)  alloc((size_t)256*2);
    u16*   b3c  = (u16*)  alloc((size_t)256*2);
    u16*   b4c  = (u16*)  alloc((size_t)256*2);
    u16*   ac   = (u16*)  alloc((size_t)8*2);
    u16*   Xbf  = (u16*)  alloc((size_t)MP*512*2);  // 20.6 MB
    u16*   h1   = (u16*)  alloc((size_t)MP*512*2);  // 20.6 MB
    u16*   P    = (u16*)  alloc((size_t)MP*256*2);  // 10.3 MB
    u16*   Q    = (u16*)  alloc((size_t)MP*256*2);  // 10.3 MB
    if (ws_size < off) return;

    hipMemsetAsync(cnt, 0, (size_t)N*4, stream);

    // prep: W^T + X cast + biases + edge scatter in one launch
    prep_all<<<dim3(16, 16, 6), dim3(32, 8), 0, stream>>>(
        d_in[iW1], d_in[iW2], d_in[iW3], d_in[iW4], d_in[iX],
        d_in[ib1], d_in[ib2], d_in[ib3], d_in[ib4], d_in[ia],
        EI, cnt, buck, E,
        WT1, WT2, WT3, WT4, Xbf, b1c, b2c, b3c, b4c, ac, N);

    // coef: dis + cdis + pad-fix (fully parallel, 1 slot/thread)
    coef<<<(N*CAP + 255)/256, 256, 0, stream>>>(cnt, buck, dis, cdis, N);

    int gm128 = (N + 127) / 128;          // 157
    int gm64  = (N + 63) / 64;            // 313
    int nodeb = (N + 31) / 32;            // 625

    // layer 1: Xbf @ W1 -> S, aggregate -> h1
    gemm128<0,0><<<gm128*4, 256, 0, stream>>>(Xbf, WT1, nullptr, S, N, 512, 512, 4);
    agg_b<512,64><<<nodeb*8, 256, 0, stream>>>(S, dis, cnt, buck, cdis, b1c, ac, h1, N);

    // layer 2: h1 @ W2 -> P ; aggregate -> Q
    gemm128<0,0><<<gm128*2, 256, 0, stream>>>(h1, WT2, nullptr, P, N, 512, 256, 2);
    agg_b<256,64><<<nodeb*4, 256, 0, stream>>>(P, dis, cnt, buck, cdis, b2c, ac, Q, N);

    // projection MLP fused: OUT = ELU(Q@W3+b3)@W4 + b4
    gemm34<<<gm64, 256, 0, stream>>>(Q, WT3, WT4, b3c, b4c, OUT, N);
}